// Round 17
// baseline (1813.211 us; speedup 1.0000x reference)
//
#include <hip/hip_runtime.h>

// Weighted furthest point sampling + gathers for KeypointDetector.
// B=16, N=16384, C=128, S=1024, SEM=20.
//
// FPS: one 1024-thread block per batch. Per step:
//   per-lane: update mind[k], track ONLY the max score bs (1 inst/pt)
//   -> in-wave f32 max (4 DPP + 2 shfls) -> candidate lanes (bs == wave
//   max, 1-2 per wave) recover their smallest matching k by bit-exact
//   register rescan and atomicMax a packed u64 (score<<32 | ~n) into the
//   per-step LDS slot -> ONE barrier -> everyone reads slot -> cur.
// u64 max == (max score, then smallest index) — numpy argmax tie-break.
//
// Output layout (float*, concatenated in reference return order):
//   [0, 49152)                  sampled_xyz      [B,S,3]
//   [49152, 49152+2097152)      sample_seg_feat  [B,C,S]
//   [2146304, 2162688)          sample_seg_label [B,S] (stored as float)

#define FPS_B   16
#define FPS_N   16384
#define FPS_C   128
#define FPS_S   1024
#define FPS_SEM 20
#define FPS_T   1024
#define FPS_PPT 16   // points per thread = N / T

typedef unsigned long long ull;

// f32 lane permute via DPP (VALU-only). CTRL: 0xB1=xor1, 0x4E=xor2,
// 0x141=row_half_mirror (xor7 merge), 0x140=row_mirror (xor15 merge).
// Proven on HW in R10-R16 runs.
template <int CTRL>
__device__ __forceinline__ float dpp_movf(float v) {
  return __uint_as_float(__builtin_amdgcn_update_dpp(
      __float_as_uint(v), __float_as_uint(v), CTRL, 0xF, 0xF, true));
}

__global__ __launch_bounds__(FPS_T)
__attribute__((amdgpu_waves_per_eu(4, 4)))
void wfps_kernel(
    const float* __restrict__ xyz,    // [B,N,3]
    const int*   __restrict__ label,  // [B,N]
    int*         __restrict__ idx_out) // [B,S]
{
  const int b = blockIdx.x;
  const int t = threadIdx.x;

  __shared__ int counts[FPS_SEM];
  __shared__ ull wmax64[FPS_S];  // per-step packed winner (init 0, single-use)

  if (t < FPS_SEM) counts[t] = 0;
  wmax64[t] = 0ull;          // T == FPS_S: each thread inits one slot;
  __syncthreads();           // packed value is always >= 0xFFFFC000 != 0

  // ---- class-frequency weights ----
  const int* lab = label + b * FPS_N;
  int mylab[FPS_PPT];
#pragma unroll
  for (int k = 0; k < FPS_PPT; ++k) {
    mylab[k] = lab[t + k * FPS_T];
    atomicAdd(&counts[mylab[k]], 1);
  }
  __syncthreads();

  // ---- my 16 points in registers; n = t + k*1024 ----
  const float* xb = xyz + b * FPS_N * 3;
  float px[FPS_PPT], py[FPS_PPT], pz[FPS_PPT], w[FPS_PPT], mind[FPS_PPT];
#pragma unroll
  for (int k = 0; k < FPS_PPT; ++k) {
    int n = t + k * FPS_T;
    px[k] = xb[n * 3 + 0];
    py[k] = xb[n * 3 + 1];
    pz[k] = xb[n * 3 + 2];
    w[k] = (float)counts[mylab[k]];
    mind[k] = 1e10f;
    asm("" : "+v"(px[k]), "+v"(py[k]), "+v"(pz[k]), "+v"(w[k]));
  }

  if (t == 0) idx_out[b * FPS_S] = 0;
  float lx = xb[0], ly = xb[1], lz = xb[2];

  // ---- serial FPS loop (unroll 2: halve loop-control overhead) ----
#pragma unroll 2
  for (int s = 1; s < FPS_S; ++s) {
    // per-lane: update mind, track max score ONLY (no index in hot loop)
    float bs = -1.0f;
#pragma unroll
    for (int k = 0; k < FPS_PPT; ++k) {
      // exact IEEE ops via _rn intrinsics: un-fusable, numpy summation order
      float dx = __fsub_rn(px[k], lx);
      float dy = __fsub_rn(py[k], ly);
      float dz = __fsub_rn(pz[k], lz);
      float d  = __fadd_rn(__fadd_rn(__fmul_rn(dx, dx), __fmul_rn(dy, dy)),
                           __fmul_rn(dz, dz));
      float m = fminf(mind[k], d);
      mind[k] = m;
      float sc = __fmul_rn(m, w[k]);
      bs = fmaxf(bs, sc);           // 1 inst/pt argmax-value tracking
    }

    // in-wave f32 max, value only: 4 DPP levels + 2 32-bit shfls.
    // scores >= +0 (w >= 1, d >= +0) so bit order == value order, no NaNs.
    float m = bs;
    m = fmaxf(m, dpp_movf<0xB1>(m));
    m = fmaxf(m, dpp_movf<0x4E>(m));
    m = fmaxf(m, dpp_movf<0x141>(m));
    m = fmaxf(m, dpp_movf<0x140>(m));
    m = fmaxf(m, __shfl_xor(m, 16, 64));
    m = fmaxf(m, __shfl_xor(m, 32, 64));

    // candidate lanes (bs == wave max, typically 1 per wave) recover their
    // smallest matching k by bit-exact register rescan (descending overwrite)
    // and publish (score<<32 | ~n) — u64 atomicMax resolves score THEN
    // smallest-n across the block in one associative op, no second phase.
    if (__float_as_uint(bs) == __float_as_uint(m)) {
      int bk = 0;
      unsigned M = __float_as_uint(m);
#pragma unroll
      for (int k = FPS_PPT - 1; k >= 0; --k)
        if (__float_as_uint(__fmul_rn(mind[k], w[k])) == M) bk = k;
      unsigned n = (unsigned)t + ((unsigned)bk << 10);
      atomicMax(&wmax64[s], ((ull)M << 32) | (ull)(~n));
    }
    __syncthreads();   // the ONLY barrier per step

    ull v = wmax64[s];
    int cur = (int)(~(unsigned)v);
    cur = __builtin_amdgcn_readfirstlane(cur);   // provably uniform

    if (t == 0) idx_out[b * FPS_S + s] = cur;

    // selected point coords: scalar/SMEM path (uniform address, cache-hot)
    const float* q = xb + 3 * cur;
    lx = q[0]; ly = q[1]; lz = q[2];
  }
}

// ---- gathers ----------------------------------------------------------------
__global__ void gather_kernel(
    const float* __restrict__ xyz,    // [B,N,3]
    const float* __restrict__ feat,   // [B,C,N]
    const int*   __restrict__ label,  // [B,N]
    const int*   __restrict__ idx,    // [B,S]
    float*       __restrict__ out)
{
  const long long FEAT = (long long)FPS_B * FPS_C * FPS_S;  // 2097152
  const int XYZN = FPS_B * FPS_S * 3;                       // 49152
  const int LABN = FPS_B * FPS_S;                           // 16384
  long long i = (long long)blockIdx.x * blockDim.x + threadIdx.x;

  if (i < FEAT) {
    int s = (int)(i & (FPS_S - 1));
    int c = (int)((i >> 10) & (FPS_C - 1));
    int b = (int)(i >> 17);
    int n = idx[b * FPS_S + s];
    out[XYZN + i] = feat[((long long)(b * FPS_C + c)) * FPS_N + n];
  } else if (i < FEAT + XYZN) {
    int j = (int)(i - FEAT);
    int d = j % 3;
    int sb = j / 3;
    int s = sb & (FPS_S - 1);
    int b = sb >> 10;
    int n = idx[b * FPS_S + s];
    out[j] = xyz[((long long)b * FPS_N + n) * 3 + d];
  } else if (i < FEAT + XYZN + LABN) {
    int j = (int)(i - FEAT - XYZN);
    int s = j & (FPS_S - 1);
    int b = j >> 10;
    int n = idx[b * FPS_S + s];
    out[FEAT + XYZN + j] = (float)label[b * FPS_N + n];
  }
}

extern "C" void kernel_launch(void* const* d_in, const int* in_sizes, int n_in,
                              void* d_out, int out_size, void* d_ws, size_t ws_size,
                              hipStream_t stream) {
  const float* xyz   = (const float*)d_in[0];
  const float* feat  = (const float*)d_in[1];
  const int*   label = (const int*)d_in[2];
  float* out = (float*)d_out;
  int*   idx = (int*)d_ws;  // B*S ints = 64 KiB scratch

  wfps_kernel<<<FPS_B, FPS_T, 0, stream>>>(xyz, label, idx);

  const long long total = (long long)FPS_B * FPS_C * FPS_S
                        + (long long)FPS_B * FPS_S * 3
                        + (long long)FPS_B * FPS_S;  // 2162688
  gather_kernel<<<(int)((total + 255) / 256), 256, 0, stream>>>(
      xyz, feat, label, idx, out);
}

// Round 18
// 1540.842 us; speedup vs baseline: 1.1768x; 1.1768x over previous
//
#include <hip/hip_runtime.h>

// Weighted furthest point sampling + gathers for KeypointDetector.
// B=16, N=16384, C=128, S=1024, SEM=20.
//
// FPS: one 1024-thread block per batch (R16 two-phase structure). Per step:
//   per-lane: update mind[k], track ONLY max score bs (1 inst/pt)
//   -> in-wave f32 max: 4 DPP xor-butterfly levels (16-group max) + 2 DPP
//      row_bcast levels (row_bcast15, row_bcast31) -> lane 63 = wave max.
//      ALL-VALU reduce: zero ds_bpermute on the critical path.
//   -> lane-63 leaders atomicMax(u32 score bits) into per-step LDS slot
//   -> barrier -> threads with bs==M (block max; ~1 wave pays) rescan
//      mind[k]*w[k] bit-exactly for smallest matching k, atomicMin(n)
//   -> barrier -> cur. 32-bit: value order == bit order (scores >= +0).
// Tie-break == numpy argmax: smallest n among score-max candidates.
//
// Output layout (float*, concatenated in reference return order):
//   [0, 49152)                  sampled_xyz      [B,S,3]
//   [49152, 49152+2097152)      sample_seg_feat  [B,C,S]
//   [2146304, 2162688)          sample_seg_label [B,S] (stored as float)

#define FPS_B   16
#define FPS_N   16384
#define FPS_C   128
#define FPS_S   1024
#define FPS_SEM 20
#define FPS_T   1024
#define FPS_PPT 16   // points per thread = N / T

typedef unsigned long long ull;

// f32 lane permute via DPP (VALU-only). CTRL: 0xB1=xor1, 0x4E=xor2,
// 0x141=row_half_mirror (xor7 merge), 0x140=row_mirror (xor15 merge),
// 0x142=row_bcast15 (lane15->lanes16-31, lane47->lanes48-63),
// 0x143=row_bcast31 (lane31->lanes32-63). bound_ctrl=1: sourceless lanes
// read 0 — harmless under fmax since all scores >= +0 and wave max > 0.
template <int CTRL>
__device__ __forceinline__ float dpp_movf(float v) {
  return __uint_as_float(__builtin_amdgcn_update_dpp(
      __float_as_uint(v), __float_as_uint(v), CTRL, 0xF, 0xF, true));
}

__global__ __launch_bounds__(FPS_T)
__attribute__((amdgpu_waves_per_eu(4, 4)))
void wfps_kernel(
    const float* __restrict__ xyz,    // [B,N,3]
    const int*   __restrict__ label,  // [B,N]
    int*         __restrict__ idx_out) // [B,S]
{
  const int b = blockIdx.x;
  const int t = threadIdx.x;
  const int lane = t & 63;

  __shared__ int counts[FPS_SEM];
  __shared__ unsigned wmax32[FPS_S];  // per-step max score bits (init 0)
  __shared__ int widx[FPS_S];         // per-step winner index (init MAX)

  if (t < FPS_SEM) counts[t] = 0;
  wmax32[t] = 0u;            // T == FPS_S: each thread inits one slot
  widx[t] = 0x7FFFFFFF;      // single-use slots: no per-step re-init
  __syncthreads();

  // ---- class-frequency weights ----
  const int* lab = label + b * FPS_N;
  int mylab[FPS_PPT];
#pragma unroll
  for (int k = 0; k < FPS_PPT; ++k) {
    mylab[k] = lab[t + k * FPS_T];
    atomicAdd(&counts[mylab[k]], 1);
  }
  __syncthreads();

  // ---- my 16 points in registers; n = t + k*1024 ----
  const float* xb = xyz + b * FPS_N * 3;
  float px[FPS_PPT], py[FPS_PPT], pz[FPS_PPT], w[FPS_PPT], mind[FPS_PPT];
#pragma unroll
  for (int k = 0; k < FPS_PPT; ++k) {
    int n = t + k * FPS_T;
    px[k] = xb[n * 3 + 0];
    py[k] = xb[n * 3 + 1];
    pz[k] = xb[n * 3 + 2];
    w[k] = (float)counts[mylab[k]];
    mind[k] = 1e10f;
    asm("" : "+v"(px[k]), "+v"(py[k]), "+v"(pz[k]), "+v"(w[k]));
  }

  if (t == 0) idx_out[b * FPS_S] = 0;
  float lx = xb[0], ly = xb[1], lz = xb[2];

  // ---- serial FPS loop (unroll 2: halve loop-control overhead) ----
#pragma unroll 2
  for (int s = 1; s < FPS_S; ++s) {
    // per-lane: update mind, track max score ONLY (no index in hot loop)
    float bs = -1.0f;
#pragma unroll
    for (int k = 0; k < FPS_PPT; ++k) {
      // exact IEEE ops via _rn intrinsics: un-fusable, numpy summation order
      float dx = __fsub_rn(px[k], lx);
      float dy = __fsub_rn(py[k], ly);
      float dz = __fsub_rn(pz[k], lz);
      float d  = __fadd_rn(__fadd_rn(__fmul_rn(dx, dx), __fmul_rn(dy, dy)),
                           __fmul_rn(dz, dz));
      float m = fminf(mind[k], d);
      mind[k] = m;
      float sc = __fmul_rn(m, w[k]);
      bs = fmaxf(bs, sc);           // 1 inst/pt argmax-value tracking
    }

    // in-wave f32 max, ALL-VALU: 4 xor-butterfly DPP levels (16-group max)
    // + row_bcast15 + row_bcast31 cascade -> lane 63 holds the wave max.
    // No ds_bpermute: removes ~240 cyc of serial DS latency per step.
    float m = bs;
    m = fmaxf(m, dpp_movf<0xB1>(m));
    m = fmaxf(m, dpp_movf<0x4E>(m));
    m = fmaxf(m, dpp_movf<0x141>(m));
    m = fmaxf(m, dpp_movf<0x140>(m));   // each 16-group reduced
    m = fmaxf(m, dpp_movf<0x142>(m));   // row1 |= g0, row3 |= g2
    m = fmaxf(m, dpp_movf<0x143>(m));   // lanes 32-63 |= max(g0,g1)

    if (lane == 63) atomicMax(&wmax32[s], __float_as_uint(m));
    __syncthreads();

    // phase 2: candidates (bs == BLOCK max; typically 1 thread, so ~1 wave
    // pays the rescan) recover smallest matching k by bit-exact register
    // recompute (descending overwrite), then race min-index.
    unsigned M = wmax32[s];
    if (__float_as_uint(bs) == M) {
      int bk = 0;
#pragma unroll
      for (int k = FPS_PPT - 1; k >= 0; --k)
        if (__float_as_uint(__fmul_rn(mind[k], w[k])) == M) bk = k;
      atomicMin(&widx[s], t + (bk << 10));
    }
    __syncthreads();

    int cur = __builtin_amdgcn_readfirstlane(widx[s]);  // provably uniform
    if (t == 0) idx_out[b * FPS_S + s] = cur;

    // selected point coords: scalar/SMEM path (uniform address, cache-hot)
    const float* q = xb + 3 * cur;
    lx = q[0]; ly = q[1]; lz = q[2];
  }
}

// ---- gathers ----------------------------------------------------------------
__global__ void gather_kernel(
    const float* __restrict__ xyz,    // [B,N,3]
    const float* __restrict__ feat,   // [B,C,N]
    const int*   __restrict__ label,  // [B,N]
    const int*   __restrict__ idx,    // [B,S]
    float*       __restrict__ out)
{
  const long long FEAT = (long long)FPS_B * FPS_C * FPS_S;  // 2097152
  const int XYZN = FPS_B * FPS_S * 3;                       // 49152
  const int LABN = FPS_B * FPS_S;                           // 16384
  long long i = (long long)blockIdx.x * blockDim.x + threadIdx.x;

  if (i < FEAT) {
    int s = (int)(i & (FPS_S - 1));
    int c = (int)((i >> 10) & (FPS_C - 1));
    int b = (int)(i >> 17);
    int n = idx[b * FPS_S + s];
    out[XYZN + i] = feat[((long long)(b * FPS_C + c)) * FPS_N + n];
  } else if (i < FEAT + XYZN) {
    int j = (int)(i - FEAT);
    int d = j % 3;
    int sb = j / 3;
    int s = sb & (FPS_S - 1);
    int b = sb >> 10;
    int n = idx[b * FPS_S + s];
    out[j] = xyz[((long long)b * FPS_N + n) * 3 + d];
  } else if (i < FEAT + XYZN + LABN) {
    int j = (int)(i - FEAT - XYZN);
    int s = j & (FPS_S - 1);
    int b = j >> 10;
    int n = idx[b * FPS_S + s];
    out[FEAT + XYZN + j] = (float)label[b * FPS_N + n];
  }
}

extern "C" void kernel_launch(void* const* d_in, const int* in_sizes, int n_in,
                              void* d_out, int out_size, void* d_ws, size_t ws_size,
                              hipStream_t stream) {
  const float* xyz   = (const float*)d_in[0];
  const float* feat  = (const float*)d_in[1];
  const int*   label = (const int*)d_in[2];
  float* out = (float*)d_out;
  int*   idx = (int*)d_ws;  // B*S ints = 64 KiB scratch

  wfps_kernel<<<FPS_B, FPS_T, 0, stream>>>(xyz, label, idx);

  const long long total = (long long)FPS_B * FPS_C * FPS_S
                        + (long long)FPS_B * FPS_S * 3
                        + (long long)FPS_B * FPS_S;  // 2162688
  gather_kernel<<<(int)((total + 255) / 256), 256, 0, stream>>>(
      xyz, feat, label, idx, out);
}